// Round 1
// baseline (59.335 us; speedup 1.0000x reference)
//
#include <hip/hip_runtime.h>

#define NQ 13
#define NL 2
#define NBATCH 512

// One batch element per 64-lane wave; grid = 512 x 64 threads (2 blocks/CU).
// No __syncthreads anywhere: all LDS traffic (ug gate table, scal) is
// intra-wave, and per-wave DS ops are processed in order by the LDS pipe.
//
// Index map (unchanged from previous version): i (13 bits) = t[8:0]:k[3:0],
// qubit q <-> i bit 12-q. Now t = r[2:0]:lane[5:0]  (r held as 8 register
// slots per lane, lane bits = qubits 3..8, r bits = qubits 0..2).
// L0 scalar factorizes as c(t) = g(r) * h(lane) with g WAVE-UNIFORM, so the
// old 4 KB sbuf staging collapses to 4 ds_bpermute of h + uniform tensor
// contractions (P/G/W below). All remaining shuffle chains carry 8
// independent r-values -> DS latency pipelines instead of serializing.

struct U2 { float r00, i00, r01, i01, r10, i10, r11, i11; };

__device__ __forceinline__ float wsum64(float v) {
    #pragma unroll
    for (int m = 32; m; m >>= 1) v += __shfl_xor(v, m, 64);
    return v;
}

// sum over lanes of (-1)^{popc(lane)} * v ; converges on all lanes
__device__ __forceinline__ float wsum64_fullpar(float v, int lane) {
    #pragma unroll
    for (int m = 32; m; m >>= 1) {
        const float y = __shfl_xor(v, m, 64);
        v = (lane & m) ? (y - v) : (v - y);
    }
    return v;
}

__global__ __launch_bounds__(64, 1) void qsim_kernel(const float* __restrict__ x,
                                                     const float* __restrict__ w,
                                                     float* __restrict__ out) {
    __shared__ U2 ug[NL * NQ];
    __shared__ float scal[20];   // S0,S1,Sr,Si then {T0,T1,Tr,Ti} per k-qubit

    const int b = blockIdx.x;
    const int lane = threadIdx.x;          // 0..63

    // ---------- Phase 0: gate matrices (lanes 0..25) ----------
    if (lane < NL * NQ) {
        const int l = lane / NQ, q = lane - l * NQ;
        const float xv = x[b * NQ + q];
        const float tx = 0.5f * xv * w[(l * NQ + q) * 3 + 0];
        const float ty = 0.5f * xv * w[(l * NQ + q) * 3 + 1];
        const float tz = 0.5f * w[(l * NQ + q) * 3 + 2];
        const float cx = __cosf(tx), sx = __sinf(tx);
        const float cy = __cosf(ty), sy = __sinf(ty);
        const float cz = __cosf(tz), sz = __sinf(tz);
        const float m00r = cy * cx,  m00i = sy * sx;
        const float m01r = -sy * cx, m01i = -cy * sx;
        const float m10r = sy * cx,  m10i = -cy * sx;
        const float m11r = cy * cx,  m11i = -sy * sx;
        U2 u;
        u.r00 = m00r * cz + m00i * sz;  u.i00 = m00i * cz - m00r * sz;
        u.r01 = m01r * cz + m01i * sz;  u.i01 = m01i * cz - m01r * sz;
        u.r10 = m10r * cz - m10i * sz;  u.i10 = m10i * cz + m10r * sz;
        u.r11 = m11r * cz - m11i * sz;  u.i11 = m11i * cz + m11r * sz;
        ug[lane] = u;
    }

    // ---------- Phase 1: per-lane h(lane) = prod L0 gates q=3..8 ----------
    float hr = 1.0f, hi = 0.0f;
    #pragma unroll
    for (int q = 3; q <= 8; ++q) {
        const U2 u = ug[q];
        const int rb = (lane >> (8 - q)) & 1;
        const float fr = rb ? u.r10 : u.r00;
        const float fi = rb ? u.i10 : u.i00;
        const float nr = hr * fr - hi * fi;
        hi = hr * fi + hi * fr;
        hr = nr;
    }

    // ---------- KS phase: block... now wave-uniform k-space scalars ----------
    // 4 groups of 16 lanes; long DS chain overlaps with the uniform VALU below.
    {
        const int k = lane & 15;
        const int g = lane >> 4;
        const int gy = k ^ (k >> 1);
        float pr = 1.0f, pi = 0.0f;
        #pragma unroll
        for (int j = 0; j < 3; ++j) {          // L0 qubits 12,11,10
            const U2 u = ug[12 - j];
            const int rbit = (gy >> j) & 1;
            const float fr = rbit ? u.r10 : u.r00;
            const float fi = rbit ? u.i10 : u.i00;
            const float nr = pr * fr - pi * fi;
            pi = pr * fi + pi * fr;
            pr = nr;
        }
        const U2 u9 = ug[9];
        const int g3 = (gy >> 3) & 1;
        const float f0r = g3 ? u9.r10 : u9.r00, f0i = g3 ? u9.i10 : u9.i00;
        const float f1r = g3 ? u9.r00 : u9.r10, f1i = g3 ? u9.i00 : u9.i10;
        float w0r = pr * f0r - pi * f0i, w0i = pr * f0i + pi * f0r;
        float w1r = pr * f1r - pi * f1i, w1i = pr * f1i + pi * f1r;
        #pragma unroll
        for (int j = 3; j >= 0; --j) {         // L1 gates q9..q12 on k-space
            const U2 u = ug[NQ + 12 - j];
            const int m = 1 << j;
            const int bit = (k >> j) & 1;
            const float a0r = bit ? u.r10 : u.r00, a0i = bit ? u.i10 : u.i00;
            const float a1r = bit ? u.r11 : u.r01, a1i = bit ? u.i11 : u.i01;
            {
                const float qr = __shfl_xor(w0r, m, 64);
                const float qi = __shfl_xor(w0i, m, 64);
                const float v0r = bit ? qr : w0r, v0i = bit ? qi : w0i;
                const float v1r = bit ? w0r : qr, v1i = bit ? w0i : qi;
                w0r = a0r * v0r - a0i * v0i + a1r * v1r - a1i * v1i;
                w0i = a0r * v0i + a0i * v0r + a1r * v1i + a1i * v1r;
            }
            {
                const float qr = __shfl_xor(w1r, m, 64);
                const float qi = __shfl_xor(w1i, m, 64);
                const float v0r = bit ? qr : w1r, v0i = bit ? qi : w1i;
                const float v1r = bit ? w1r : qr, v1i = bit ? w1i : qi;
                w1r = a0r * v0r - a0i * v0i + a1r * v1r - a1i * v1i;
                w1i = a0r * v0i + a0i * v0r + a1r * v1i + a1i * v1r;
            }
        }
        const float p0v = w0r * w0r + w0i * w0i;
        const float p1v = w1r * w1r + w1i * w1i;
        const float rrv = w0r * w1r + w0i * w1i;
        const float riv = w0i * w1r - w0r * w1i;
        float tks[5];
        tks[0] = (g == 0) ? p0v : (g == 1) ? p1v : (g == 2) ? rrv : riv;
        #pragma unroll
        for (int j = 3; j >= 0; --j) {         // suffix-parity reduction (16 lanes)
            const int m = 1 << j;
            const int neg = (k >> j) & 1;
            const int cnt = 4 - j;
            const float pre = tks[cnt - 1];
            const float pp = __shfl_xor(pre, m, 64);
            tks[cnt] = neg ? (pp - pre) : (pre - pp);
            tks[cnt - 1] = pre + pp;
            #pragma unroll
            for (int e = 0; e < 4; ++e)
                if (e < cnt - 1) tks[e] += __shfl_xor(tks[e], m, 64);
        }
        if (k == 0) {
            scal[g] = tks[0];
            #pragma unroll
            for (int idx = 0; idx < 4; ++idx)
                scal[4 + idx * 4 + g] = tks[1 + idx];
        }
    }

    // ---------- wave-uniform g(r) = prod L0 gates q=0..2 (col 0) ----------
    const U2 V0 = ug[0], V1 = ug[1], V2 = ug[2];
    float grr[8], gii[8];
    #pragma unroll
    for (int r = 0; r < 8; ++r) {
        const int b0 = (r >> 2) & 1, b1 = (r >> 1) & 1, b2 = r & 1;
        const float ar = b0 ? V0.r10 : V0.r00, ai = b0 ? V0.i10 : V0.i00;
        const float br = b1 ? V1.r10 : V1.r00, bi = b1 ? V1.i10 : V1.i00;
        const float cr = b2 ? V2.r10 : V2.r00, ci = b2 ? V2.i10 : V2.i00;
        const float t1r = ar * br - ai * bi, t1i = ar * bi + ai * br;
        grr[r] = t1r * cr - t1i * ci;
        gii[r] = t1r * ci + t1i * cr;
    }

    // ---------- Phase 2: fused chain + L1 q0..q2, all-uniform except h ----------
    // d(t) = sum_{a,bb,c} u0L1[r0][a] u1L1[r1][bb] u2L1[r2][c] * g(rp) h(lane')
    // rp = (a, a^bb, bb^c); lane' = ((c^t5)<<5)|gray(lane). Everything except
    // h is wave-uniform -> precontract to W[r][c], gather h with 4 bpermutes.
    const U2 U0 = ug[NQ + 0], U1 = ug[NQ + 1], U2c = ug[NQ + 2];
    float Pr[2][2][2], Pi[2][2][2];            // P[r1][a][c] = sum_bb u1*g
    #pragma unroll
    for (int r1 = 0; r1 < 2; ++r1) {
        const float B0r = r1 ? U1.r10 : U1.r00, B0i = r1 ? U1.i10 : U1.i00;
        const float B1r = r1 ? U1.r11 : U1.r01, B1i = r1 ? U1.i11 : U1.i01;
        #pragma unroll
        for (int a = 0; a < 2; ++a) {
            #pragma unroll
            for (int c = 0; c < 2; ++c) {
                const int rp0 = (a << 2) | (a << 1) | c;              // bb=0
                const int rp1 = (a << 2) | ((a ^ 1) << 1) | (1 ^ c);  // bb=1
                Pr[r1][a][c] = B0r * grr[rp0] - B0i * gii[rp0] + B1r * grr[rp1] - B1i * gii[rp1];
                Pi[r1][a][c] = B0r * gii[rp0] + B0i * grr[rp0] + B1r * gii[rp1] + B1i * grr[rp1];
            }
        }
    }
    float Gr2[2][2][2], Gi2[2][2][2];          // G[r0][r1][c] = sum_a u0*P
    #pragma unroll
    for (int r0 = 0; r0 < 2; ++r0) {
        const float A0r = r0 ? U0.r10 : U0.r00, A0i = r0 ? U0.i10 : U0.i00;
        const float A1r = r0 ? U0.r11 : U0.r01, A1i = r0 ? U0.i11 : U0.i01;
        #pragma unroll
        for (int r1 = 0; r1 < 2; ++r1) {
            #pragma unroll
            for (int c = 0; c < 2; ++c) {
                Gr2[r0][r1][c] = A0r * Pr[r1][0][c] - A0i * Pi[r1][0][c]
                               + A1r * Pr[r1][1][c] - A1i * Pi[r1][1][c];
                Gi2[r0][r1][c] = A0r * Pi[r1][0][c] + A0i * Pr[r1][0][c]
                               + A1r * Pi[r1][1][c] + A1i * Pr[r1][1][c];
            }
        }
    }
    float Wr[8][2], Wi[8][2];                  // W[r][c] = u2L1[r2][c] * G
    #pragma unroll
    for (int r = 0; r < 8; ++r) {
        const int r0 = (r >> 2) & 1, r1 = (r >> 1) & 1, r2 = r & 1;
        #pragma unroll
        for (int c = 0; c < 2; ++c) {
            const float cr = c ? (r2 ? U2c.r11 : U2c.r01) : (r2 ? U2c.r10 : U2c.r00);
            const float ci = c ? (r2 ? U2c.i11 : U2c.i01) : (r2 ? U2c.i10 : U2c.i00);
            Wr[r][c] = cr * Gr2[r0][r1][c] - ci * Gi2[r0][r1][c];
            Wi[r][c] = cr * Gi2[r0][r1][c] + ci * Gr2[r0][r1][c];
        }
    }
    const int gl = (lane ^ (lane >> 1)) & 31;
    const float h0r = __shfl(hr, gl, 64),      h0i = __shfl(hi, gl, 64);
    const float h1r = __shfl(hr, 32 | gl, 64), h1i = __shfl(hi, 32 | gl, 64);
    const int t5 = (lane >> 5) & 1;
    const float hc0r = t5 ? h1r : h0r, hc0i = t5 ? h1i : h0i;  // hh[0^t5]
    const float hc1r = t5 ? h0r : h1r, hc1i = t5 ? h0i : h1i;  // hh[1^t5]
    float dr[8], di[8];
    #pragma unroll
    for (int r = 0; r < 8; ++r) {
        dr[r] = Wr[r][0] * hc0r - Wi[r][0] * hc0i + Wr[r][1] * hc1r - Wi[r][1] * hc1i;
        di[r] = Wr[r][0] * hc0i + Wi[r][0] * hc0r + Wr[r][1] * hc1i + Wi[r][1] * hc1r;
    }

    // ---------- Phase 3: L1 lane-bit gates q3..q7 (8-way ILP chains) ----------
    #pragma unroll
    for (int q = 3; q <= 7; ++q) {
        const U2 u = ug[NQ + q];
        const int m = 1 << (8 - q);            // 32,16,8,4,2
        const int bit = (lane >> (8 - q)) & 1;
        const float a0r = bit ? u.r11 : u.r00, a0i = bit ? u.i11 : u.i00;
        const float b0r = bit ? u.r10 : u.r01, b0i = bit ? u.i10 : u.i01;
        #pragma unroll
        for (int r = 0; r < 8; ++r) {
            const float pr = __shfl_xor(dr[r], m, 64);
            const float pi = __shfl_xor(di[r], m, 64);
            const float nr = a0r * dr[r] - a0i * di[r] + b0r * pr - b0i * pi;
            di[r] = a0r * di[r] + a0i * dr[r] + b0r * pi + b0i * pr;
            dr[r] = nr;
        }
    }

    // ---------- Phase 4+5: L1 gate q8 -> rank-2 coeffs -> A,B,C,D, ptot ----------
    const U2 u8 = ug[NQ + 8];
    const int t0 = lane & 1;
    const float c1r = t0 ? u8.r10 : u8.r00, c1i = t0 ? u8.i10 : u8.i00;
    const float c2r = t0 ? u8.r11 : u8.r01, c2i = t0 ? u8.i11 : u8.i01;
    const float S0 = scal[0], S1 = scal[1], S2 = scal[2], S3 = scal[3];
    float Av[8], Bv[8], Cv[8], Dv[8], pt[8];
    #pragma unroll
    for (int r = 0; r < 8; ++r) {
        const float pr = __shfl_xor(dr[r], 1, 64);
        const float pi = __shfl_xor(di[r], 1, 64);
        const float o1r = t0 ? pr : dr[r], o1i = t0 ? pi : di[r];
        const float o2r = t0 ? dr[r] : pr, o2i = t0 ? di[r] : pi;
        const float uur = c1r * o1r - c1i * o1i, uui = c1r * o1i + c1i * o1r;
        const float vvr = c2r * o2r - c2i * o2i, vvi = c2r * o2i + c2i * o2r;
        Av[r] = uur * uur + uui * uui;
        Bv[r] = vvr * vvr + vvi * vvi;
        Cv[r] = 2.0f * (uur * vvr + uui * vvi);
        Dv[r] = -2.0f * (uui * vvr - uur * vvi);
        pt[r] = Av[r] * S0 + Bv[r] * S1 + Cv[r] * S2 + Dv[r] * S3;
    }

    // ---------- Phase 6: register r-sums + wave butterflies, 13 outputs ----------
    // r-sign tables: o=0 -> (-1)^{r2bit}=r>=4; o=1 -> (-1)^{r2^r1}; o>=2 -> (-1)^{popc r}
    const float a0 = (pt[0] + pt[1] + pt[2] + pt[3]) - (pt[4] + pt[5] + pt[6] + pt[7]);
    const float a1 = (pt[0] + pt[1] + pt[6] + pt[7]) - (pt[2] + pt[3] + pt[4] + pt[5]);
    const float a2 = (pt[0] + pt[3] + pt[5] + pt[6]) - (pt[1] + pt[2] + pt[4] + pt[7]);
    const float As = (Av[0] + Av[3] + Av[5] + Av[6]) - (Av[1] + Av[2] + Av[4] + Av[7]);
    const float Bs = (Bv[0] + Bv[3] + Bv[5] + Bv[6]) - (Bv[1] + Bv[2] + Bv[4] + Bv[7]);
    const float Cs = (Cv[0] + Cv[3] + Cv[5] + Cv[6]) - (Cv[1] + Cv[2] + Cv[4] + Cv[7]);
    const float Ds = (Dv[0] + Dv[3] + Dv[5] + Dv[6]) - (Dv[1] + Dv[2] + Dv[4] + Dv[7]);

    const float ev0 = wsum64(a0);
    const float ev1 = wsum64(a1);

    // suffix-parity chain over lane bits 5..0: tr6[c] = sum (-1)^{par(top c bits)} a2
    float tr6[7];
    tr6[0] = a2;
    #pragma unroll
    for (int lev = 0; lev < 6; ++lev) {
        const int m = 32 >> lev;
        const int neg = (lane & m) ? 1 : 0;
        const int n = lev + 1;
        const float pre = tr6[n - 1];
        const float pp = __shfl_xor(pre, m, 64);
        tr6[n] = neg ? (pp - pre) : (pre - pp);
        tr6[n - 1] = pre + pp;
        #pragma unroll
        for (int e = 0; e < 6; ++e)
            if (e < n - 1) tr6[e] += __shfl_xor(tr6[e], m, 64);
    }

    const float FAs = wsum64_fullpar(As, lane);
    const float FBs = wsum64_fullpar(Bs, lane);
    const float FCs = wsum64_fullpar(Cs, lane);
    const float FDs = wsum64_fullpar(Ds, lane);

    if (lane == 0) {
        float* o = out + b * NQ;
        o[0] = ev0;   o[1] = ev1;
        o[2] = tr6[0]; o[3] = tr6[1]; o[4] = tr6[2]; o[5] = tr6[3];
        o[6] = tr6[4]; o[7] = tr6[5]; o[8] = tr6[6];
        o[9]  = FAs * scal[4]  + FBs * scal[5]  + FCs * scal[6]  + FDs * scal[7];
        o[10] = FAs * scal[8]  + FBs * scal[9]  + FCs * scal[10] + FDs * scal[11];
        o[11] = FAs * scal[12] + FBs * scal[13] + FCs * scal[14] + FDs * scal[15];
        o[12] = FAs * scal[16] + FBs * scal[17] + FCs * scal[18] + FDs * scal[19];
    }
}

extern "C" void kernel_launch(void* const* d_in, const int* in_sizes, int n_in,
                              void* d_out, int out_size, void* d_ws, size_t ws_size,
                              hipStream_t stream) {
    const float* x = (const float*)d_in[0];   // (512, 13) float32
    const float* w = (const float*)d_in[1];   // (2, 13, 3) float32
    float* out = (float*)d_out;               // (512, 13) float32
    qsim_kernel<<<NBATCH, 64, 0, stream>>>(x, w, out);
}